// Round 2
// baseline (279.372 us; speedup 1.0000x reference)
//
#include <hip/hip_runtime.h>
#include <hip/hip_bf16.h>

#define SELF_D 36
#define ENT_D  28
#define HID    256
#define OBS    1688   // 36 + 28*59
#define NE     59     // 20 opp + 19 par + 20 noisy
#define RPB    4      // rows per block-iteration
#define GRID   2048

// ws float layout
#define WS_A     0        // 36*256
#define WS_B     9216     // 28*256
#define WS_C     16384    // 256
#define WS_MSEL  16640    // 108  (36 x 3)   } contiguous 360 = Mfull[120][3]
#define WS_MENT  16748    // 252  (3 x 28 x 3)
#define WS_CG    17000    // 3
#define WS_WATT  17008    // 28
#define WS_TOTAL 17040

__global__ __launch_bounds__(256)
void setup_kernel(const float* __restrict__ Watt, const float* __restrict__ We,
                  const float* __restrict__ be,  const float* __restrict__ Wse,
                  const float* __restrict__ bse, const float* __restrict__ Wg,
                  const float* __restrict__ bg,  const float* __restrict__ Wo,
                  const float* __restrict__ bo,  float* __restrict__ ws) {
  const int blk = blockIdx.x;
  const int c = threadIdx.x;
  if (blk < 36) {
    int k = blk;
    float acc = 0.f;
    for (int r = 0; r < 256; ++r) acc += We[k*256 + r] * Wo[r*256 + c];
    for (int r = 0; r < 256; ++r) acc += (Wse[k*256 + r] + Wse[(36+k)*256 + r]) * Wo[(256+r)*256 + c];
    ws[WS_A + k*256 + c] = acc;
  } else if (blk < 64) {
    int k = blk - 36;
    float acc = 0.f;
    for (int r = 0; r < 256; ++r) acc += We[(36+k)*256 + r] * Wo[r*256 + c];
    ws[WS_B + k*256 + c] = acc;
  } else if (blk == 64) {
    float acc = bo[c];
    for (int r = 0; r < 256; ++r) acc += be[r] * Wo[r*256 + c];
    for (int r = 0; r < 256; ++r) acc += bse[r] * Wo[(256+r)*256 + c];
    ws[WS_C + c] = acc;
  } else {
    for (int t = c; t < 391; t += 256) {
      if (t < 108) {
        int k = t / 3, j = t - 3*k;
        float acc = 0.f;
        for (int r = 0; r < 256; ++r) {
          float wg = Wg[r*3 + j] + Wg[(256+r)*3 + j] + Wg[(512+r)*3 + j];
          acc += We[k*256 + r] * wg;
        }
        ws[WS_MSEL + t] = acc;
      } else if (t < 360) {
        int idx = t - 108;
        int g = idx / 84, rem = idx - 84*g;
        int k = rem / 3, j = rem - 3*k;
        float acc = 0.f;
        for (int r = 0; r < 256; ++r) acc += We[(36+k)*256 + r] * Wg[(256*g + r)*3 + j];
        ws[WS_MENT + idx] = acc;
      } else if (t < 363) {
        int j = t - 360;
        float acc = bg[j];
        for (int r = 0; r < 256; ++r)
          acc += be[r] * (Wg[r*3 + j] + Wg[(256+r)*3 + j] + Wg[(512+r)*3 + j]);
        ws[WS_CG + j] = acc;
      } else {
        int k = t - 363;
        ws[WS_WATT + k] = Watt[36 + k];
      }
    }
  }
}

// Slot layout for entities: slot = g*20 + idx; slot 39 is a DUMMY (par has 19).
// entity_index(slot) = slot - (slot >= 40 ? 1 : 0); dummy gets e=0.
__global__ __launch_bounds__(256, 4)
void main_kernel(const float* __restrict__ x, const float* __restrict__ ws,
                 float* __restrict__ out, int B) {
  __shared__ float rows[RPB][OBS];     // 27008 B
  __shared__ float satt[RPB][64];      // unnormalized exp(l - m_row), slot-indexed
  __shared__ float sebar[RPB][84];     // normalized per-group weighted means [g*28+k]
  __shared__ float se2[RPB][28];
  __shared__ float ptl[RPB][3][8];     // gate-logit partials
  __shared__ float sW[28];
  __shared__ float sMfull[360];        // [120][3]
  __shared__ float scg[3];

  const int tid = threadIdx.x;

  for (int t = tid; t < 28;  t += 256) sW[t]    = ws[WS_WATT + t];
  for (int t = tid; t < 360; t += 256) sMfull[t] = ws[WS_MSEL + t];
  if (tid < 3) scg[tid] = ws[WS_CG + tid];

  float Areg[36], Breg[28];
#pragma unroll
  for (int k = 0; k < 36; ++k) Areg[k] = ws[WS_A + k*256 + tid];
#pragma unroll
  for (int k = 0; k < 28; ++k) Breg[k] = ws[WS_B + k*256 + tid];
  const float cc = ws[WS_C + tid];

  const int ngroups = B / RPB;

  // prologue: prefetch first group into registers
  float4 pf[7];
  {
    const float4* src = (const float4*)(x + (size_t)blockIdx.x * (RPB * OBS));
#pragma unroll
    for (int i = 0; i < 7; ++i) {
      int idx = tid + i * 256;
      if (idx < (RPB * OBS) / 4) pf[i] = src[idx];
    }
  }

  for (int grp = blockIdx.x; grp < ngroups; grp += GRID) {
    __syncthreads();  // previous iteration's readers done (no-op cost first iter; also fences one-time LDS init)

    // stage registers -> LDS
    {
      float4* dst = (float4*)&rows[0][0];
#pragma unroll
      for (int i = 0; i < 7; ++i) {
        int idx = tid + i * 256;
        if (idx < (RPB * OBS) / 4) dst[idx] = pf[i];
      }
    }
    // issue next group's global loads (in flight across all compute below)
    {
      int ngrp = grp + GRID;
      if (ngrp < ngroups) {
        const float4* src = (const float4*)(x + (size_t)ngrp * (RPB * OBS));
#pragma unroll
        for (int i = 0; i < 7; ++i) {
          int idx = tid + i * 256;
          if (idx < (RPB * OBS) / 4) pf[i] = src[idx];
        }
      }
    }
    __syncthreads();  // rows ready

    // Phase B: wave r = row, lane = slot. Logit + row-global max + exp.
    {
      int r = tid >> 6, sl = tid & 63;
      int ent = sl - (sl >= 40 ? 1 : 0);
      bool valid = (sl < 60) && (sl != 39);
      float l = -1e30f;
      if (valid) {
        const float* e = &rows[r][SELF_D + ENT_D * ent];
        int k0 = ent;  // ent % 28
        if (k0 >= 28) k0 -= 28;
        if (k0 >= 28) k0 -= 28;
        float acc = 0.f;
#pragma unroll
        for (int t = 0; t < ENT_D; ++t) {
          int k = k0 + t;
          if (k >= ENT_D) k -= ENT_D;   // rotated component: stride-29 banks, conflict-free
          acc += e[k] * sW[k];
        }
        l = acc;
      }
      float m = l;
#pragma unroll
      for (int off = 32; off; off >>= 1) m = fmaxf(m, __shfl_xor(m, off));
      if (sl < 60) satt[r][sl] = valid ? __expf(l - m) : 0.f;  // dummy slot 39 -> 0
    }
    __syncthreads();

    // Phase D: unnormalized weighted sums + normalize. task = (r, g, k), 336 tasks.
    for (int task = tid; task < RPB * 84; task += 256) {
      int r = task / 84, m2 = task - 84 * r;
      int g = m2 / 28, k = m2 - 28 * g;
      int sbase = g * 20;
      float us = 0.f, uv = 0.f;
#pragma unroll
      for (int i2 = 0; i2 < 20; ++i2) {
        int sl = sbase + i2;
        int ent = sl - (sl >= 40 ? 1 : 0);
        float e = satt[r][sl];
        float v = rows[r][SELF_D + ENT_D * ent + k];
        us += e; uv += e * v;
      }
      sebar[r][m2] = uv / us;
    }
    __syncthreads();

    // Phase E: gate-logit partials. 96 lanes: (r, j, chunk of 15 over 120-vec).
    if (tid < RPB * 24) {
      int r = tid / 24, rem = tid - 24 * r;
      int j = rem / 8, ch = rem - 8 * j;
      int c0 = ch * 15;
      float acc = 0.f;
#pragma unroll
      for (int q = 0; q < 15; ++q) {
        int c = c0 + q;
        float v = (c < SELF_D) ? rows[r][c] : sebar[r][c - SELF_D];
        acc += v * sMfull[c * 3 + j];
      }
      ptl[r][j][ch] = acc;
    }
    __syncthreads();

    // Phase F: combine partials -> gate softmax -> gated mix. 112 lanes (r,k).
    if (tid < RPB * 28) {
      int r = tid / 28, k = tid - 28 * r;
      float l0 = scg[0], l1 = scg[1], l2 = scg[2];
#pragma unroll
      for (int ch = 0; ch < 8; ++ch) {
        l0 += ptl[r][0][ch]; l1 += ptl[r][1][ch]; l2 += ptl[r][2][ch];
      }
      float mm = fmaxf(l0, fmaxf(l1, l2));
      float e0 = __expf(l0 - mm), e1 = __expf(l1 - mm), e2 = __expf(l2 - mm);
      float inv = 1.f / (e0 + e1 + e2);
      se2[r][k] = (e0 * sebar[r][k] + e1 * sebar[r][28 + k] + e2 * sebar[r][56 + k]) * inv;
    }
    __syncthreads();

    // Phase G: out[row][c] = cc + self@A[:,c] + e2@B[:,c]; A/B in registers, float4 LDS reads.
    {
      float* o = out + (size_t)grp * (RPB * HID) + tid;
#pragma unroll
      for (int r = 0; r < RPB; ++r) {
        float acc = cc;
        const float4* sv = (const float4*)&rows[r][0];
#pragma unroll
        for (int q = 0; q < 9; ++q) {
          float4 v = sv[q];
          acc += v.x * Areg[4*q] + v.y * Areg[4*q+1] + v.z * Areg[4*q+2] + v.w * Areg[4*q+3];
        }
        const float4* ev = (const float4*)&se2[r][0];
#pragma unroll
        for (int q = 0; q < 7; ++q) {
          float4 v = ev[q];
          acc += v.x * Breg[4*q] + v.y * Breg[4*q+1] + v.z * Breg[4*q+2] + v.w * Breg[4*q+3];
        }
        o[(size_t)r * HID] = acc;
      }
    }
  }
}

extern "C" void kernel_launch(void* const* d_in, const int* in_sizes, int n_in,
                              void* d_out, int out_size, void* d_ws, size_t ws_size,
                              hipStream_t stream) {
  const float* x    = (const float*)d_in[0];
  const float* Watt = (const float*)d_in[1];
  const float* We   = (const float*)d_in[3];
  const float* be   = (const float*)d_in[4];
  const float* Wse  = (const float*)d_in[5];
  const float* bse  = (const float*)d_in[6];
  const float* Wg   = (const float*)d_in[7];
  const float* bg   = (const float*)d_in[8];
  const float* Wo   = (const float*)d_in[9];
  const float* bo   = (const float*)d_in[10];
  float* out = (float*)d_out;
  float* ws  = (float*)d_ws;
  const int B = in_sizes[0] / OBS;

  setup_kernel<<<66, 256, 0, stream>>>(Watt, We, be, Wse, bse, Wg, bg, Wo, bo, ws);
  main_kernel<<<GRID, 256, 0, stream>>>(x, ws, out, B);
}

// Round 3
// 151.328 us; speedup vs baseline: 1.8461x; 1.8461x over previous
//
#include <hip/hip_runtime.h>
#include <hip/hip_bf16.h>

#define SELF_D 36
#define ENT_D  28
#define HID    256
#define OBS    1688   // 36 + 28*59
#define RPB    4      // rows per block

// ws float layout
#define WS_A     0        // 36*256 (k-major; source for AT)
#define WS_B     9216     // 28*256
#define WS_C     16384    // 256
#define WS_MSEL  16640    // 108  } contiguous 360 = Mfull[120][3]
#define WS_MENT  16748    // 252
#define WS_CG    17000    // 3
#define WS_WATT  17008    // 28
#define WS_AT    17040    // 256*36, c-major: AT[c][k]; byte off 68160 = 16B-aligned
#define WS_BT    26256    // 256*28, c-major: BT[c][k]; byte off 105024 = 16B-aligned
#define WS_TOTAL 33424

__global__ __launch_bounds__(256)
void setup_kernel(const float* __restrict__ Watt, const float* __restrict__ We,
                  const float* __restrict__ be,  const float* __restrict__ Wse,
                  const float* __restrict__ bse, const float* __restrict__ Wg,
                  const float* __restrict__ bg,  const float* __restrict__ Wo,
                  const float* __restrict__ bo,  float* __restrict__ ws) {
  const int blk = blockIdx.x;
  const int c = threadIdx.x;
  if (blk < 36) {
    int k = blk;
    float acc = 0.f;
    for (int r = 0; r < 256; ++r) acc += We[k*256 + r] * Wo[r*256 + c];
    for (int r = 0; r < 256; ++r) acc += (Wse[k*256 + r] + Wse[(36+k)*256 + r]) * Wo[(256+r)*256 + c];
    ws[WS_A + k*256 + c] = acc;
    ws[WS_AT + c*36 + k] = acc;
  } else if (blk < 64) {
    int k = blk - 36;
    float acc = 0.f;
    for (int r = 0; r < 256; ++r) acc += We[(36+k)*256 + r] * Wo[r*256 + c];
    ws[WS_B + k*256 + c] = acc;
    ws[WS_BT + c*28 + k] = acc;
  } else if (blk == 64) {
    float acc = bo[c];
    for (int r = 0; r < 256; ++r) acc += be[r] * Wo[r*256 + c];
    for (int r = 0; r < 256; ++r) acc += bse[r] * Wo[(256+r)*256 + c];
    ws[WS_C + c] = acc;
  } else {
    for (int t = c; t < 391; t += 256) {
      if (t < 108) {
        int k = t / 3, j = t - 3*k;
        float acc = 0.f;
        for (int r = 0; r < 256; ++r) {
          float wg = Wg[r*3 + j] + Wg[(256+r)*3 + j] + Wg[(512+r)*3 + j];
          acc += We[k*256 + r] * wg;
        }
        ws[WS_MSEL + t] = acc;
      } else if (t < 360) {
        int idx = t - 108;
        int g = idx / 84, rem = idx - 84*g;
        int k = rem / 3, j = rem - 3*k;
        float acc = 0.f;
        for (int r = 0; r < 256; ++r) acc += We[(36+k)*256 + r] * Wg[(256*g + r)*3 + j];
        ws[WS_MENT + idx] = acc;
      } else if (t < 363) {
        int j = t - 360;
        float acc = bg[j];
        for (int r = 0; r < 256; ++r)
          acc += be[r] * (Wg[r*3 + j] + Wg[(256+r)*3 + j] + Wg[(512+r)*3 + j]);
        ws[WS_CG + j] = acc;
      } else {
        int k = t - 363;
        ws[WS_WATT + k] = Watt[36 + k];
      }
    }
  }
}

// Entity slots: slot = g*20 + idx; slot 39 is a DUMMY (par group has 19).
// entity_index(slot) = slot - (slot >= 40); dummy gets weight 0.
__global__ __launch_bounds__(256)
void main_kernel(const float* __restrict__ x, const float* __restrict__ ws,
                 float* __restrict__ out) {
  __shared__ __align__(16) float rows[RPB][OBS];   // 27008 B
  __shared__ __align__(16) float satt[RPB][64];    // exp(l - m_row), slot-indexed
  __shared__ __align__(16) float sebar[RPB][84];   // per-group weighted means [g*28+k]
  __shared__ __align__(16) float se2[RPB][28];
  __shared__ __align__(16) float ptl[RPB][3][8];
  __shared__ __align__(16) float sW[28];
  __shared__ __align__(16) float sMfull[360];      // [120][3]
  __shared__ float scg[3];

  const int tid = threadIdx.x;
  const size_t row0 = (size_t)blockIdx.x * RPB;

  // Stage 4 contiguous rows (1688 float4) straight into LDS — no VGPRs used.
  {
    const float* src = x + row0 * OBS;
#pragma unroll
    for (int i = 0; i < 7; ++i) {
      int idx = tid + i * 256;
      if (idx < (RPB * OBS) / 4) {
        __builtin_amdgcn_global_load_lds(
            (const __attribute__((address_space(1))) void*)(src + idx * 4),
            (__attribute__((address_space(3))) void*)(&rows[0][0] + idx * 4),
            16, 0, 0);
      }
    }
  }

  // Small derived tensors (overlap with staging; L2-hot)
  for (int t = tid; t < 360; t += 256) sMfull[t] = ws[WS_MSEL + t];
  for (int t = tid; t < 28;  t += 256) sW[t]    = ws[WS_WATT + t];
  if (tid < 3) scg[tid] = ws[WS_CG + tid];
  const float cc = ws[WS_C + tid];

  __syncthreads();  // drains vmcnt (lds-loads) + lgkm

  // Phase B: wave r = row, lane = slot. Logit + row-global max + exp.
  {
    int r = tid >> 6, sl = tid & 63;
    int ent = sl - (sl >= 40 ? 1 : 0);
    bool valid = (sl < 60) && (sl != 39);
    float l = -1e30f;
    if (valid) {
      const float* e = &rows[r][SELF_D + ENT_D * ent];
      int k0 = ent;
      if (k0 >= 28) k0 -= 28;
      if (k0 >= 28) k0 -= 28;
      float acc = 0.f;
#pragma unroll
      for (int t = 0; t < ENT_D; ++t) {
        int k = k0 + t;
        if (k >= ENT_D) k -= ENT_D;   // rotated: breaks stride-28 bank aliasing
        acc += e[k] * sW[k];
      }
      l = acc;
    }
    float m = l;
#pragma unroll
    for (int off = 32; off; off >>= 1) m = fmaxf(m, __shfl_xor(m, off));
    if (sl < 60) satt[r][sl] = valid ? __expf(l - m) : 0.f;
  }
  __syncthreads();

  // Phase D: weighted sums + normalize. 336 tasks (r,g,k).
  for (int task = tid; task < RPB * 84; task += 256) {
    int r = task / 84, m2 = task - 84 * r;
    int g = m2 / 28, k = m2 - 28 * g;
    int sbase = g * 20;
    float us = 0.f, uv = 0.f;
#pragma unroll
    for (int i2 = 0; i2 < 20; ++i2) {
      int sl = sbase + i2;
      int ent = sl - (sl >= 40 ? 1 : 0);
      float e = satt[r][sl];
      float v = rows[r][SELF_D + ENT_D * ent + k];
      us += e; uv += e * v;
    }
    sebar[r][m2] = uv / us;
  }
  __syncthreads();

  // Phase E: gate-logit partials. 96 lanes (r, j, chunk of 15 over 120).
  if (tid < RPB * 24) {
    int r = tid / 24, rem = tid - 24 * r;
    int j = rem / 8, ch = rem - 8 * j;
    int c0 = ch * 15;
    float acc = 0.f;
#pragma unroll
    for (int q = 0; q < 15; ++q) {
      int c = c0 + q;
      float v = (c < SELF_D) ? rows[r][c] : sebar[r][c - SELF_D];
      acc += v * sMfull[c * 3 + j];
    }
    ptl[r][j][ch] = acc;
  }
  __syncthreads();

  // Phase F: gate softmax + gated mix. 112 lanes (r,k).
  if (tid < RPB * 28) {
    int r = tid / 28, k = tid - 28 * r;
    float l0 = scg[0], l1 = scg[1], l2 = scg[2];
#pragma unroll
    for (int ch = 0; ch < 8; ++ch) {
      l0 += ptl[r][0][ch]; l1 += ptl[r][1][ch]; l2 += ptl[r][2][ch];
    }
    float mm = fmaxf(l0, fmaxf(l1, l2));
    float e0 = __expf(l0 - mm), e1 = __expf(l1 - mm), e2 = __expf(l2 - mm);
    float inv = 1.f / (e0 + e1 + e2);
    se2[r][k] = (e0 * sebar[r][k] + e1 * sebar[r][28 + k] + e2 * sebar[r][56 + k]) * inv;
  }
  __syncthreads();

  // Phase G: out[row][c] = cc + self@AT[c] + e2@BT[c].
  // AT/BT rows are per-thread contiguous float4 (L2-hot); rows/se2 via LDS b128 broadcast.
  {
    const float4* At = (const float4*)(ws + WS_AT + tid * 36);  // 9 x float4
    const float4* Bt = (const float4*)(ws + WS_BT + tid * 28);  // 7 x float4
    float acc[RPB] = {cc, cc, cc, cc};
#pragma unroll
    for (int q = 0; q < 9; ++q) {
      float4 a = At[q];
#pragma unroll
      for (int r = 0; r < RPB; ++r) {
        float4 s = ((const float4*)&rows[r][0])[q];
        acc[r] += a.x * s.x + a.y * s.y + a.z * s.z + a.w * s.w;
      }
    }
#pragma unroll
    for (int q = 0; q < 7; ++q) {
      float4 b = Bt[q];
#pragma unroll
      for (int r = 0; r < RPB; ++r) {
        float4 s = ((const float4*)&se2[r][0])[q];
        acc[r] += b.x * s.x + b.y * s.y + b.z * s.z + b.w * s.w;
      }
    }
    float* o = out + row0 * HID + tid;
#pragma unroll
    for (int r = 0; r < RPB; ++r) o[(size_t)r * HID] = acc[r];
  }
}

extern "C" void kernel_launch(void* const* d_in, const int* in_sizes, int n_in,
                              void* d_out, int out_size, void* d_ws, size_t ws_size,
                              hipStream_t stream) {
  const float* x    = (const float*)d_in[0];
  const float* Watt = (const float*)d_in[1];
  const float* We   = (const float*)d_in[3];
  const float* be   = (const float*)d_in[4];
  const float* Wse  = (const float*)d_in[5];
  const float* bse  = (const float*)d_in[6];
  const float* Wg   = (const float*)d_in[7];
  const float* bg   = (const float*)d_in[8];
  const float* Wo   = (const float*)d_in[9];
  const float* bo   = (const float*)d_in[10];
  float* out = (float*)d_out;
  float* ws  = (float*)d_ws;
  const int B = in_sizes[0] / OBS;

  setup_kernel<<<66, 256, 0, stream>>>(Watt, We, be, Wse, bse, Wg, bg, Wo, bo, ws);
  main_kernel<<<B / RPB, 256, 0, stream>>>(x, ws, out);
}

// Round 4
// 104.083 us; speedup vs baseline: 2.6841x; 1.4539x over previous
//
#include <hip/hip_runtime.h>
#include <hip/hip_bf16.h>

#define SELF_D 36
#define ENT_D  28
#define HID    256
#define OBS    1688   // 36 + 28*59
#define NWAVES 8192   // pool kernel: 2048 blocks x 4 waves

// ws float layout
#define WS_A     0        // 36*256 (k-major)
#define WS_B     9216     // 28*256
#define WS_C     16384    // 256
#define WS_MSEL  16640    // 108  } contiguous 360 = Mfull[120][3]
#define WS_MENT  16748    // 252
#define WS_CG    17000    // 3
#define WS_WATT  17008    // 28
#define WS_AT    17040    // 256*36 c-major AT[c][k]
#define WS_BT    26256    // 256*28 c-major BT[c][k]
#define WS_TOTAL 33424

__global__ __launch_bounds__(256)
void setup_kernel(const float* __restrict__ Watt, const float* __restrict__ We,
                  const float* __restrict__ be,  const float* __restrict__ Wse,
                  const float* __restrict__ bse, const float* __restrict__ Wg,
                  const float* __restrict__ bg,  const float* __restrict__ Wo,
                  const float* __restrict__ bo,  float* __restrict__ ws) {
  const int blk = blockIdx.x;
  const int c = threadIdx.x;
  if (blk < 36) {
    int k = blk;
    float acc = 0.f;
    for (int r = 0; r < 256; ++r) acc += We[k*256 + r] * Wo[r*256 + c];
    for (int r = 0; r < 256; ++r) acc += (Wse[k*256 + r] + Wse[(36+k)*256 + r]) * Wo[(256+r)*256 + c];
    ws[WS_A + k*256 + c] = acc;
    ws[WS_AT + c*36 + k] = acc;
  } else if (blk < 64) {
    int k = blk - 36;
    float acc = 0.f;
    for (int r = 0; r < 256; ++r) acc += We[(36+k)*256 + r] * Wo[r*256 + c];
    ws[WS_B + k*256 + c] = acc;
    ws[WS_BT + c*28 + k] = acc;
  } else if (blk == 64) {
    float acc = bo[c];
    for (int r = 0; r < 256; ++r) acc += be[r] * Wo[r*256 + c];
    for (int r = 0; r < 256; ++r) acc += bse[r] * Wo[(256+r)*256 + c];
    ws[WS_C + c] = acc;
  } else {
    for (int t = c; t < 391; t += 256) {
      if (t < 108) {
        int k = t / 3, j = t - 3*k;
        float acc = 0.f;
        for (int r = 0; r < 256; ++r) {
          float wg = Wg[r*3 + j] + Wg[(256+r)*3 + j] + Wg[(512+r)*3 + j];
          acc += We[k*256 + r] * wg;
        }
        ws[WS_MSEL + t] = acc;
      } else if (t < 360) {
        int idx = t - 108;
        int g = idx / 84, rem = idx - 84*g;
        int k = rem / 3, j = rem - 3*k;
        float acc = 0.f;
        for (int r = 0; r < 256; ++r) acc += We[(36+k)*256 + r] * Wg[(256*g + r)*3 + j];
        ws[WS_MENT + idx] = acc;
      } else if (t < 363) {
        int j = t - 360;
        float acc = bg[j];
        for (int r = 0; r < 256; ++r)
          acc += be[r] * (Wg[r*3 + j] + Wg[(256+r)*3 + j] + Wg[(512+r)*3 + j]);
        ws[WS_CG + j] = acc;
      } else {
        int k = t - 363;
        ws[WS_WATT + k] = Watt[36 + k];
      }
    }
  }
}

// Entity slots: slot = g*20 + i; slot 39 is a DUMMY (par has 19 entities).
// entity(slot) = slot - (slot >= 40). Wave-per-row, barrier-free.
__global__ __launch_bounds__(256)
void pool_kernel(const float* __restrict__ x, const float* __restrict__ ws,
                 float* __restrict__ out, int B) {
  __shared__ float sM[360];              // Mfull[120][3]
  __shared__ float satt[4][64];          // per-wave
  __shared__ float sebar[4][84];         // per-wave

  const int tid = threadIdx.x;
  const int w = tid >> 6, ln = tid & 63;

  for (int t = tid; t < 360; t += 256) sM[t] = ws[WS_MSEL + t];
  __syncthreads();                       // the only block barrier

  const float* Wp = ws + WS_WATT;        // uniform -> scalar loads
  const float cg0 = ws[WS_CG + 0], cg1 = ws[WS_CG + 1], cg2 = ws[WS_CG + 2];

  const int ent_b = ln - (ln >= 40 ? 1 : 0);
  const bool valid_b = (ln < 60) && (ln != 39);

  for (int row = blockIdx.x * 4 + w; row < B; row += NWAVES) {
    const float* xr = x + (size_t)row * OBS;

    // --- attention logits: lane = slot; 7 x float4 + dot(28) ---
    float l = -1e30f;
    {
      const float* e = xr + SELF_D + ENT_D * (valid_b ? ent_b : 0);
      float acc = 0.f;
#pragma unroll
      for (int q = 0; q < 7; ++q) {
        float4 v = ((const float4*)e)[q];
        acc += v.x*Wp[4*q] + v.y*Wp[4*q+1] + v.z*Wp[4*q+2] + v.w*Wp[4*q+3];
      }
      if (valid_b) l = acc;
    }
    float m = l;
#pragma unroll
    for (int off = 32; off; off >>= 1) m = fmaxf(m, __shfl_xor(m, off));
    satt[w][ln] = valid_b ? __expf(l - m) : 0.f;

    // --- per-(g,k) weighted means; 84 tasks in 2 passes; reads x again (L2/L3-hot) ---
#pragma unroll
    for (int pass = 0; pass < 2; ++pass) {
      int t = ln + pass * 64;
      if (t < 84) {
        int g = t / 28, k = t - 28 * g;
        int e0 = g * 20 - (g >> 1);                 // base entity: 0, 20, 39
        const float* vb = xr + SELF_D + ENT_D * e0 + k;
        const float* pa = &satt[w][g * 20];
        float us = 0.f, uv = 0.f;
#pragma unroll
        for (int i = 0; i < 20; ++i) {
          float pp = pa[i];
          float vv = vb[ENT_D * i];                 // imm-offset loads off one base
          us += pp; uv += pp * vv;
        }
        sebar[w][t] = uv / us;
      }
    }

    // --- gate logits: lanes (j = ln>>4 < 3, ch = ln&15 < 15); c = q*15 + ch ---
    float gl = 0.f;
    {
      int j = ln >> 4, ch = ln & 15;
      if (j < 3 && ch < 15) {
#pragma unroll
        for (int q = 0; q < 8; ++q) {
          int c = q * 15 + ch;
          float v = (c < SELF_D) ? xr[c] : sebar[w][c - SELF_D];
          gl += v * sM[c * 3 + j];
        }
      }
#pragma unroll
      for (int off = 1; off < 16; off <<= 1) gl += __shfl_xor(gl, off);
    }
    float l0 = __shfl(gl, 0)  + cg0;
    float l1 = __shfl(gl, 16) + cg1;
    float l2 = __shfl(gl, 32) + cg2;
    float mm = fmaxf(l0, fmaxf(l1, l2));
    float e0x = __expf(l0 - mm), e1x = __expf(l1 - mm), e2x = __expf(l2 - mm);
    float inv = 1.f / (e0x + e1x + e2x);

    // --- emit f = [self(36), ebar-mix(28)] into out[row][0:64] ---
    float fv;
    if (ln < SELF_D) {
      fv = xr[ln];
    } else {
      int k = ln - SELF_D;
      fv = (e0x * sebar[w][k] + e1x * sebar[w][28 + k] + e2x * sebar[w][56 + k]) * inv;
    }
    out[(size_t)row * HID + ln] = fv;
  }
}

// out[row][c] = cc[c] + f[0:36]@AT[c] + f[36:64]@BT[c], f read in-place from out[row][0:64].
#define PR_ROWS 32
#define PR_CH   8
__global__ __launch_bounds__(256)
void proj_kernel(const float* __restrict__ ws, float* __restrict__ out) {
  __shared__ __align__(16) float sf[PR_CH][64];
  const int tid = threadIdx.x;

  float4 Av[9], Bv[7];
#pragma unroll
  for (int q = 0; q < 9; ++q) Av[q] = ((const float4*)(ws + WS_AT + tid * 36))[q];
#pragma unroll
  for (int q = 0; q < 7; ++q) Bv[q] = ((const float4*)(ws + WS_BT + tid * 28))[q];
  const float cc = ws[WS_C + tid];

  const size_t row0 = (size_t)blockIdx.x * PR_ROWS;
  for (int chk = 0; chk < PR_ROWS / PR_CH; ++chk) {
    const size_t rbase = row0 + chk * PR_CH;
    if (tid < PR_CH * 16) {                       // stage 8 rows x 64 floats
      int r = tid >> 4, q = tid & 15;
      ((float4*)&sf[r][0])[q] = ((const float4*)(out + (rbase + r) * HID))[q];
    }
    __syncthreads();
#pragma unroll
    for (int r = 0; r < PR_CH; ++r) {
      float acc = cc;
      const float4* f4 = (const float4*)&sf[r][0];
#pragma unroll
      for (int q = 0; q < 9; ++q) {
        float4 s = f4[q];
        acc += Av[q].x*s.x + Av[q].y*s.y + Av[q].z*s.z + Av[q].w*s.w;
      }
#pragma unroll
      for (int q = 0; q < 7; ++q) {
        float4 s = f4[9 + q];
        acc += Bv[q].x*s.x + Bv[q].y*s.y + Bv[q].z*s.z + Bv[q].w*s.w;
      }
      out[(rbase + r) * HID + tid] = acc;
    }
    __syncthreads();
  }
}

extern "C" void kernel_launch(void* const* d_in, const int* in_sizes, int n_in,
                              void* d_out, int out_size, void* d_ws, size_t ws_size,
                              hipStream_t stream) {
  const float* x    = (const float*)d_in[0];
  const float* Watt = (const float*)d_in[1];
  const float* We   = (const float*)d_in[3];
  const float* be   = (const float*)d_in[4];
  const float* Wse  = (const float*)d_in[5];
  const float* bse  = (const float*)d_in[6];
  const float* Wg   = (const float*)d_in[7];
  const float* bg   = (const float*)d_in[8];
  const float* Wo   = (const float*)d_in[9];
  const float* bo   = (const float*)d_in[10];
  float* out = (float*)d_out;
  float* ws  = (float*)d_ws;
  const int B = in_sizes[0] / OBS;

  setup_kernel<<<66, 256, 0, stream>>>(Watt, We, be, Wse, bse, Wg, bg, Wo, bo, ws);
  pool_kernel<<<NWAVES / 4, 256, 0, stream>>>(x, ws, out, B);
  proj_kernel<<<B / PR_ROWS, 256, 0, stream>>>(ws, out);
}